// Round 6
// baseline (246.274 us; speedup 1.0000x reference)
//
#include <hip/hip_runtime.h>
#include <hip/hip_bf16.h>
#include <math.h>

#define NB 64
#define HH 512
#define WW 512
#define KK 31
#define PP 15
#define NROWS (NB * HH)         // 32768 rows total
#define ROWS_PER_WAVE 4
#define NSTRIP2 32              // pass-2 strips per image
#define SR2 (HH / NSTRIP2)      // 16 rows per strip

typedef _Float16 f16;
typedef f16 f16x8 __attribute__((ext_vector_type(8)));
typedef f16 f16x2 __attribute__((ext_vector_type(2)));

// ws layout (fast path):
//   part[0..2047]    = per-block inter   (2048 pass-2 blocks)
//   part[2048..4095] = per-block union
//   H (fp16) at byte offset 32768: 32 MB horizontal box-sum field
#define WS_NEED (32768 + (size_t)NROWS * WW * 2)

// ---------------- Pass 1: H(r,x) = sum_{c=x-15..x+15} mask[r][c] (zero-pad), fp16 out ----
__global__ __launch_bounds__(256, 8) void hrow_kernel(const float* __restrict__ mask,
                                                      f16* __restrict__ H) {
    const int gw   = (blockIdx.x * 256 + threadIdx.x) >> 6;   // global wave id, 0..8191
    const int lane = threadIdx.x & 63;

    for (int k = 0; k < ROWS_PER_WAVE; ++k) {
        const size_t r = (size_t)gw * ROWS_PER_WAVE + k;
        const float* row = mask + r * WW;
        const int xbase = lane * 8;
        const float4 a = *(const float4*)(row + xbase);
        const float4 b = *(const float4*)(row + xbase + 4);

        // in-lane inclusive prefix of 8 elements
        float s0 = a.x;
        float s1 = s0 + a.y;
        float s2 = s1 + a.z;
        float s3 = s2 + a.w;
        float s4 = s3 + b.x;
        float s5 = s4 + b.y;
        float s6 = s5 + b.z;
        float s7 = s6 + b.w;

        // wave-inclusive scan of lane totals
        float incl = s7;
        #pragma unroll
        for (int off = 1; off < 64; off <<= 1) {
            float t = __shfl_up(incl, off);
            if (lane >= off) incl += t;
        }
        const float base = incl - s7;          // exclusive prefix
        s0 += base; s1 += base; s2 += base; s3 += base;
        s4 += base; s5 += base; s6 += base; s7 += base;
        // s_j = M[8*lane + j] (inclusive row prefix)

        const float total = __shfl(incl, 63);  // M[511]

        float hiv[8], lov[8];
        // hi taps: M[x+15]. x=8l+j: j=0 -> lane+1 elem7; j>=1 -> lane+2 elem j-1
        hiv[0] = __shfl_down(s7, 1);
        hiv[1] = __shfl_down(s0, 2);
        hiv[2] = __shfl_down(s1, 2);
        hiv[3] = __shfl_down(s2, 2);
        hiv[4] = __shfl_down(s3, 2);
        hiv[5] = __shfl_down(s4, 2);
        hiv[6] = __shfl_down(s5, 2);
        hiv[7] = __shfl_down(s6, 2);
        // lo taps: M[x-16] -> lane-2 elem j
        lov[0] = __shfl_up(s0, 2);
        lov[1] = __shfl_up(s1, 2);
        lov[2] = __shfl_up(s2, 2);
        lov[3] = __shfl_up(s3, 2);
        lov[4] = __shfl_up(s4, 2);
        lov[5] = __shfl_up(s5, 2);
        lov[6] = __shfl_up(s6, 2);
        lov[7] = __shfl_up(s7, 2);

        f16x8 hv;
        #pragma unroll
        for (int j = 0; j < 8; ++j) {
            const int x = xbase + j;
            const float mhi = (x + PP > WW - 1) ? total : hiv[j];
            const float mlo = (x - PP - 1 >= 0) ? lov[j] : 0.0f;
            hv[j] = (f16)(mhi - mlo);
        }
        *(f16x8*)(H + r * WW + xbase) = hv;
    }
}

// ---------------- Pass 2: running vertical 31-sum of H + fused epilogue, float2/thread ----
__device__ inline float2 loadH2(const f16* p) {
    const f16x2 v = *(const f16x2*)p;
    return make_float2((float)v[0], (float)v[1]);
}

__global__ __launch_bounds__(256, 8) void dice_kernel(
        const float* __restrict__ pred,
        const float* __restrict__ mask,
        const f16* __restrict__ H,
        float* __restrict__ part) {
    const int strip = blockIdx.x;           // 0..31 (16-row strip)
    const int b     = blockIdx.y;
    const int t     = threadIdx.x;
    const int c     = t * 2;                // 2 columns per thread
    const int wave  = t >> 6;
    const int lane  = t & 63;

    __shared__ float red[8];

    const f16*   Hb = H    + (size_t)b * HH * WW;
    const float* mb = mask + (size_t)b * HH * WW;
    const float* pb = pred + (size_t)b * HH * WW;
    const int y0 = strip * SR2;

    // init: B = sum_{r=y0-15}^{y0+14} H[r][c..c+1] (rows clamped to >=0)
    float2 B = make_float2(0.f, 0.f);
    {
        const int rlo = (y0 - PP < 0) ? 0 : y0 - PP;
        const int rhi = y0 + PP - 1;        // always < HH
        for (int r = rlo; r <= rhi; ++r) {
            const float2 h = loadH2(Hb + (size_t)r * WW + c);
            B.x += h.x; B.y += h.y;
        }
    }

    float2 inter2 = make_float2(0.f, 0.f);
    float2 uni2   = make_float2(0.f, 0.f);
    const float2 zero2 = make_float2(0.f, 0.f);
    const float inv2 = 1.0f / (float)(KK * KK);

    #pragma unroll
    for (int i = 0; i < SR2; ++i) {
        const int y = y0 + i;
        const float2 he = (y + PP < HH) ? loadH2(Hb + (size_t)(y + PP) * WW + c) : zero2;
        const float2 hl = (y - PP >= 0) ? loadH2(Hb + (size_t)(y - PP) * WW + c) : zero2;
        const float2 m  = *(const float2*)(mb + (size_t)y * WW + c);
        const float2 p  = *(const float2*)(pb + (size_t)y * WW + c);

        B.x += he.x; B.y += he.y;

        const float w0 = 1.0f + 5.0f * fabsf(B.x * inv2 - m.x);
        const float w1 = 1.0f + 5.0f * fabsf(B.y * inv2 - m.y);
        const float sg0 = 1.0f / (1.0f + __expf(-p.x));
        const float sg1 = 1.0f / (1.0f + __expf(-p.y));

        inter2.x += sg0 * m.x * w0;  uni2.x += (sg0 + m.x) * w0;
        inter2.y += sg1 * m.y * w1;  uni2.y += (sg1 + m.y) * w1;

        B.x -= hl.x; B.y -= hl.y;
    }

    float inter = inter2.x + inter2.y;
    float uni   = uni2.x + uni2.y;
    #pragma unroll
    for (int off = 32; off > 0; off >>= 1) {
        inter += __shfl_down(inter, off);
        uni   += __shfl_down(uni, off);
    }
    if (lane == 0) { red[wave] = inter; red[4 + wave] = uni; }
    __syncthreads();
    if (t == 0) {
        const float ti = red[0] + red[1] + red[2] + red[3];
        const float tu = red[4] + red[5] + red[6] + red[7];
        const int bid = b * NSTRIP2 + strip;
        part[bid]        = ti;
        part[2048 + bid] = tu;
    }
}

// ---------------- Fallback (round-3 monolithic) if ws too small ---------------
#define NSTRIP 16
#define SROWS (HH / NSTRIP)
#define RPB 4
#define NROUND (SROWS / RPB)
#define PSTR 544

__global__ __launch_bounds__(512, 8) void dice_strip_kernel(
        const float* __restrict__ pred,
        const float* __restrict__ mask,
        float* __restrict__ part) {
    const int strip = blockIdx.x;
    const int b     = blockIdx.y;
    const int x     = threadIdx.x;
    const int wave  = x >> 6;
    const int lane  = x & 63;

    __shared__ float wtot[RPB * 8];
    __shared__ float Pbuf[RPB * PSTR];
    __shared__ float red[16];

    const float* mbase = mask + (size_t)b * HH * WW;
    const float* pbase = pred + (size_t)b * HH * WW;
    const int y0 = strip * SROWS;

    if (x < 16) {
        #pragma unroll
        for (int r = 0; r < RPB; ++r) Pbuf[r * PSTR + x] = 0.0f;
    }
    float vcarry = 0.0f;
    {
        const int rlo = (y0 - PP - 1 < 0) ? 0 : y0 - PP - 1;
        const int rhi = (y0 + PP - 1 > HH - 1) ? HH - 1 : y0 + PP - 1;
        for (int r = rlo; r <= rhi; ++r) vcarry += mbase[r * WW + x];
    }
    float inter = 0.0f, uni = 0.0f;
    for (int j = 0; j < NROUND; ++j) {
        const int y = y0 + j * RPB;
        float en[RPB], lv[RPB], mc[RPB], pv[RPB];
        #pragma unroll
        for (int r = 0; r < RPB; ++r) {
            const int ra = y + r + PP;
            const int rs = y + r - PP - 1;
            en[r] = (ra < HH) ? mbase[ra * WW + x] : 0.0f;
            lv[r] = (rs >= 0) ? mbase[rs * WW + x] : 0.0f;
            mc[r] = mbase[(y + r) * WW + x];
            pv[r] = pbase[(y + r) * WW + x];
        }
        float incl[RPB];
        {
            float run = vcarry;
            #pragma unroll
            for (int r = 0; r < RPB; ++r) { run += en[r] - lv[r]; incl[r] = run; }
            vcarry = run;
        }
        #pragma unroll
        for (int off = 1; off < 64; off <<= 1) {
            float tt[RPB];
            #pragma unroll
            for (int r = 0; r < RPB; ++r) tt[r] = __shfl_up(incl[r], off);
            #pragma unroll
            for (int r = 0; r < RPB; ++r) if (lane >= off) incl[r] += tt[r];
        }
        if (lane == 63) {
            #pragma unroll
            for (int r = 0; r < RPB; ++r) wtot[r * 8 + wave] = incl[r];
        }
        __syncthreads();
        float bm[RPB];
        #pragma unroll
        for (int r = 0; r < RPB; ++r) bm[r] = (lane < wave) ? wtot[r * 8 + lane] : 0.0f;
        #pragma unroll
        for (int off = 1; off < 64; off <<= 1) {
            #pragma unroll
            for (int r = 0; r < RPB; ++r) bm[r] += __shfl_xor(bm[r], off);
        }
        #pragma unroll
        for (int r = 0; r < RPB; ++r) Pbuf[r * PSTR + 16 + x] = bm[r] + incl[r];
        if (wave == 7) {
            #pragma unroll
            for (int r = 0; r < RPB; ++r) {
                const float p511 = bm[r] + wtot[r * 8 + 7];
                if (lane >= 48) Pbuf[r * PSTR + 528 + (lane - 48)] = p511;
            }
        }
        __syncthreads();
        #pragma unroll
        for (int r = 0; r < RPB; ++r) {
            const float hsum = Pbuf[r * PSTR + 16 + x + PP] - Pbuf[r * PSTR + x];
            const float avg  = hsum * (1.0f / (float)(KK * KK));
            const float m    = mc[r];
            const float w    = 1.0f + 5.0f * fabsf(avg - m);
            const float sg   = 1.0f / (1.0f + __expf(-pv[r]));
            inter += sg * m * w;
            uni   += (sg + m) * w;
        }
    }
    #pragma unroll
    for (int off = 32; off > 0; off >>= 1) {
        inter += __shfl_down(inter, off);
        uni   += __shfl_down(uni, off);
    }
    if (lane == 0) { red[wave] = inter; red[8 + wave] = uni; }
    __syncthreads();
    if (x == 0) {
        float ti = 0.0f, tu = 0.0f;
        #pragma unroll
        for (int w2 = 0; w2 < 8; ++w2) { ti += red[w2]; tu += red[8 + w2]; }
        const int bid = b * NSTRIP + strip;
        part[bid] = ti;
        part[NB * NSTRIP + bid] = tu;
    }
}

// ---------------- Final reduction ---------------
__global__ void dice_final_kernel(const float* __restrict__ part,
                                  float* __restrict__ out, int nper, int stride) {
    const int t = threadIdx.x;  // 64 threads, one per image
    float inter = 0.0f, uni = 0.0f;
    for (int s = 0; s < nper; ++s) {
        inter += part[t * nper + s];
        uni   += part[stride + t * nper + s];
    }
    float wd = 1.0f - (2.0f * inter + 0.5f) / (uni + 0.5f);
    #pragma unroll
    for (int off = 32; off > 0; off >>= 1) wd += __shfl_down(wd, off);
    if (t == 0) out[0] = wd * (1.0f / (float)NB);
}

extern "C" void kernel_launch(void* const* d_in, const int* in_sizes, int n_in,
                              void* d_out, int out_size, void* d_ws, size_t ws_size,
                              hipStream_t stream) {
    const float* pred = (const float*)d_in[0];
    const float* mask = (const float*)d_in[1];
    float* out  = (float*)d_out;
    float* part = (float*)d_ws;
    f16*   H    = (f16*)((char*)d_ws + 32768);

    if (ws_size >= WS_NEED) {
        hrow_kernel<<<2048, 256, 0, stream>>>(mask, H);     // 32 waves/CU
        dim3 grid2(NSTRIP2, NB);                            // 2048 blocks
        dice_kernel<<<grid2, 256, 0, stream>>>(pred, mask, H, part);
        dice_final_kernel<<<1, 64, 0, stream>>>(part, out, NSTRIP2, 2048);
    } else {
        dim3 grid2(NSTRIP, NB);
        dice_strip_kernel<<<grid2, 512, 0, stream>>>(pred, mask, part);
        dice_final_kernel<<<1, 64, 0, stream>>>(part, out, NSTRIP, NB * NSTRIP);
    }
}

// Round 7
// 170.580 us; speedup vs baseline: 1.4437x; 1.4437x over previous
//
#include <hip/hip_runtime.h>
#include <math.h>

#define NB 64
#define HH 512
#define WW 512
#define KK 31
#define PP 15
#define TS 32                 // output rows per strip
#define NSTRIP (HH / TS)      // 16 strips per image
#define HR (TS + KK - 1)      // 62 H rows held in LDS

typedef _Float16 f16;
typedef f16 f16x8 __attribute__((ext_vector_type(8)));
typedef f16 f16x4 __attribute__((ext_vector_type(4)));

// ws layout: part[0..1023] = per-block inter, part[1024..2047] = per-block union
// block id = b * NSTRIP + strip

__global__ __launch_bounds__(512, 2) void dice_fused_kernel(
        const float* __restrict__ pred,
        const float* __restrict__ mask,
        float* __restrict__ part) {
    const int strip = blockIdx.x;
    const int b     = blockIdx.y;
    const int t     = threadIdx.x;
    const int wave  = t >> 6;
    const int lane  = t & 63;

    __shared__ f16 Hs[HR][WW];    // 62 x 512 fp16 = 63.5 KB : horizontal box sums
    __shared__ f16 Ms[TS][WW];    // 32 x 512 fp16 = 32 KB   : center mask rows
    __shared__ float red[16];

    const float* mb = mask + (size_t)b * HH * WW;
    const float* pb = pred + (size_t)b * HH * WW;
    const int y0 = strip * TS;

    // ================= Phase 1: H rows [y0-15, y0+46] via wave-shuffle scan =========
    const int xbase = lane * 8;
    #pragma unroll
    for (int k = 0; k < 8; ++k) {
        const int r = k * 8 + wave;          // LDS H-row index, 0..61
        if (r >= HR) break;                  // only k=7, waves 6..7
        const int gy = y0 + r - PP;
        if (gy < 0 || gy >= HH) {
            f16x8 z = {(f16)0, (f16)0, (f16)0, (f16)0, (f16)0, (f16)0, (f16)0, (f16)0};
            *(f16x8*)&Hs[r][xbase] = z;
            continue;
        }
        const float* row = mb + (size_t)gy * WW;
        const float4 a  = *(const float4*)(row + xbase);
        const float4 bb = *(const float4*)(row + xbase + 4);

        // in-lane inclusive prefix of 8 elements
        float s0 = a.x;
        float s1 = s0 + a.y;
        float s2 = s1 + a.z;
        float s3 = s2 + a.w;
        float s4 = s3 + bb.x;
        float s5 = s4 + bb.y;
        float s6 = s5 + bb.z;
        float s7 = s6 + bb.w;

        // wave-inclusive scan of lane totals
        float incl = s7;
        #pragma unroll
        for (int off = 1; off < 64; off <<= 1) {
            float tt = __shfl_up(incl, off);
            if (lane >= off) incl += tt;
        }
        const float base = incl - s7;        // exclusive prefix
        s0 += base; s1 += base; s2 += base; s3 += base;
        s4 += base; s5 += base; s6 += base; s7 += base;
        // s_j = M[8*lane + j] inclusive row prefix

        const float total = __shfl(incl, 63);

        float hiv[8], lov[8];
        // hi taps: M[x+15]. x=8l+j: j=0 -> lane+1 elem7; j>=1 -> lane+2 elem j-1
        hiv[0] = __shfl_down(s7, 1);
        hiv[1] = __shfl_down(s0, 2);
        hiv[2] = __shfl_down(s1, 2);
        hiv[3] = __shfl_down(s2, 2);
        hiv[4] = __shfl_down(s3, 2);
        hiv[5] = __shfl_down(s4, 2);
        hiv[6] = __shfl_down(s5, 2);
        hiv[7] = __shfl_down(s6, 2);
        // lo taps: M[x-16] -> lane-2 elem j
        lov[0] = __shfl_up(s0, 2);
        lov[1] = __shfl_up(s1, 2);
        lov[2] = __shfl_up(s2, 2);
        lov[3] = __shfl_up(s3, 2);
        lov[4] = __shfl_up(s4, 2);
        lov[5] = __shfl_up(s5, 2);
        lov[6] = __shfl_up(s6, 2);
        lov[7] = __shfl_up(s7, 2);

        f16x8 hv;
        #pragma unroll
        for (int j = 0; j < 8; ++j) {
            const int x = xbase + j;
            const float mhi = (x + PP > WW - 1) ? total : hiv[j];
            const float mlo = (x - PP - 1 >= 0) ? lov[j] : 0.0f;
            hv[j] = (f16)(mhi - mlo);
        }
        *(f16x8*)&Hs[r][xbase] = hv;

        // stash center mask rows (gy in [y0, y0+TS)) as fp16
        const int cr = r - PP;
        if (cr >= 0 && cr < TS) {
            f16x8 mv;
            mv[0] = (f16)a.x;  mv[1] = (f16)a.y;  mv[2] = (f16)a.z;  mv[3] = (f16)a.w;
            mv[4] = (f16)bb.x; mv[5] = (f16)bb.y; mv[6] = (f16)bb.z; mv[7] = (f16)bb.w;
            *(f16x8*)&Ms[cr][xbase] = mv;
        }
    }
    __syncthreads();

    // ================= Phase 2: vertical running 31-sum + fused epilogue ===========
    // thread: 4 cols x 8 rows.  q = col group, g = row group.
    const int q  = t & 127;
    const int g  = t >> 7;               // 0..3
    const int c  = q * 4;
    const int r0 = g * 8;                // first output row (strip-relative)

    float4 B = make_float4(0.f, 0.f, 0.f, 0.f);
    #pragma unroll
    for (int j = 0; j < KK - 1; ++j) {   // H rows idx r0 .. r0+29
        const f16x4 h = *(const f16x4*)&Hs[r0 + j][c];
        B.x += (float)h[0]; B.y += (float)h[1]; B.z += (float)h[2]; B.w += (float)h[3];
    }

    float4 I4 = make_float4(0.f, 0.f, 0.f, 0.f);
    float4 U4 = make_float4(0.f, 0.f, 0.f, 0.f);
    const float inv2 = 1.0f / (float)(KK * KK);

    #pragma unroll
    for (int i = 0; i < 8; ++i) {
        const int y = y0 + r0 + i;
        const f16x4 he = *(const f16x4*)&Hs[r0 + i + (KK - 1)][c];
        const f16x4 hl = *(const f16x4*)&Hs[r0 + i][c];
        const f16x4 m4 = *(const f16x4*)&Ms[r0 + i][c];
        const float4 p4 = *(const float4*)(pb + (size_t)y * WW + c);

        B.x += (float)he[0]; B.y += (float)he[1]; B.z += (float)he[2]; B.w += (float)he[3];

        const float m0 = (float)m4[0], m1 = (float)m4[1], m2 = (float)m4[2], m3 = (float)m4[3];
        const float w0 = 1.0f + 5.0f * fabsf(B.x * inv2 - m0);
        const float w1 = 1.0f + 5.0f * fabsf(B.y * inv2 - m1);
        const float w2 = 1.0f + 5.0f * fabsf(B.z * inv2 - m2);
        const float w3 = 1.0f + 5.0f * fabsf(B.w * inv2 - m3);
        const float sg0 = 1.0f / (1.0f + __expf(-p4.x));
        const float sg1 = 1.0f / (1.0f + __expf(-p4.y));
        const float sg2 = 1.0f / (1.0f + __expf(-p4.z));
        const float sg3 = 1.0f / (1.0f + __expf(-p4.w));

        I4.x += sg0 * m0 * w0;  U4.x += (sg0 + m0) * w0;
        I4.y += sg1 * m1 * w1;  U4.y += (sg1 + m1) * w1;
        I4.z += sg2 * m2 * w2;  U4.z += (sg2 + m2) * w2;
        I4.w += sg3 * m3 * w3;  U4.w += (sg3 + m3) * w3;

        B.x -= (float)hl[0]; B.y -= (float)hl[1]; B.z -= (float)hl[2]; B.w -= (float)hl[3];
    }

    // ================= Block reduction -> per-block partials ======================
    float inter = I4.x + I4.y + I4.z + I4.w;
    float uni   = U4.x + U4.y + U4.z + U4.w;
    #pragma unroll
    for (int off = 32; off > 0; off >>= 1) {
        inter += __shfl_down(inter, off);
        uni   += __shfl_down(uni, off);
    }
    if (lane == 0) { red[wave] = inter; red[8 + wave] = uni; }
    __syncthreads();
    if (t == 0) {
        float ti = 0.f, tu = 0.f;
        #pragma unroll
        for (int w2 = 0; w2 < 8; ++w2) { ti += red[w2]; tu += red[8 + w2]; }
        const int bid = b * NSTRIP + strip;
        part[bid] = ti;
        part[NB * NSTRIP + bid] = tu;
    }
}

// ---------------- Final reduction ---------------
__global__ void dice_final_kernel(const float* __restrict__ part,
                                  float* __restrict__ out) {
    const int t = threadIdx.x;  // 64 threads, one per image
    float inter = 0.0f, uni = 0.0f;
    #pragma unroll
    for (int s = 0; s < NSTRIP; ++s) {
        inter += part[t * NSTRIP + s];
        uni   += part[NB * NSTRIP + t * NSTRIP + s];
    }
    float wd = 1.0f - (2.0f * inter + 0.5f) / (uni + 0.5f);
    #pragma unroll
    for (int off = 32; off > 0; off >>= 1) wd += __shfl_down(wd, off);
    if (t == 0) out[0] = wd * (1.0f / (float)NB);
}

extern "C" void kernel_launch(void* const* d_in, const int* in_sizes, int n_in,
                              void* d_out, int out_size, void* d_ws, size_t ws_size,
                              hipStream_t stream) {
    const float* pred = (const float*)d_in[0];
    const float* mask = (const float*)d_in[1];
    float* out  = (float*)d_out;
    float* part = (float*)d_ws;   // 2048 floats = 8 KB

    dim3 grid(NSTRIP, NB);        // 16 x 64 = 1024 blocks
    dice_fused_kernel<<<grid, 512, 0, stream>>>(pred, mask, part);
    dice_final_kernel<<<1, 64, 0, stream>>>(part, out);
}

// Round 8
// 152.813 us; speedup vs baseline: 1.6116x; 1.1163x over previous
//
#include <hip/hip_runtime.h>
#include <math.h>

#define NB 64
#define HH 512
#define WW 512
#define KK 31
#define PP 15
#define TS 32                 // output rows per strip
#define NSTRIP (HH / TS)      // 16 strips per image
#define HR (TS + KK - 1)      // 62 H rows held in LDS

typedef _Float16 f16;
typedef f16 f16x8 __attribute__((ext_vector_type(8)));
typedef f16 f16x4 __attribute__((ext_vector_type(4)));

// ws layout: part[0..1023] = per-block inter, part[1024..2047] = per-block union
// block id = b * NSTRIP + strip

__global__ __launch_bounds__(512, 4) void dice_fused_kernel(
        const float* __restrict__ pred,
        const float* __restrict__ mask,
        float* __restrict__ part) {
    const int strip = blockIdx.x;
    const int b     = blockIdx.y;
    const int t     = threadIdx.x;
    const int wave  = t >> 6;
    const int lane  = t & 63;

    __shared__ f16 Hs[HR][WW];    // 62 x 512 fp16 = 63.5 KB : horizontal box sums
    __shared__ float red[16];     // total ~63.6 KB -> 2 blocks/CU

    const float* mb = mask + (size_t)b * HH * WW;
    const float* pb = pred + (size_t)b * HH * WW;
    const int y0 = strip * TS;

    // ================= Phase 1: H rows [y0-15, y0+46] via wave-shuffle scan =========
    const int xbase = lane * 8;
    #pragma unroll
    for (int k = 0; k < 8; ++k) {
        const int r = k * 8 + wave;          // LDS H-row index, 0..61
        if (r >= HR) break;                  // only k=7, waves 6..7
        const int gy = y0 + r - PP;
        if (gy < 0 || gy >= HH) {
            f16x8 z = {(f16)0, (f16)0, (f16)0, (f16)0, (f16)0, (f16)0, (f16)0, (f16)0};
            *(f16x8*)&Hs[r][xbase] = z;
            continue;
        }
        const float* row = mb + (size_t)gy * WW;
        const float4 a  = *(const float4*)(row + xbase);
        const float4 bb = *(const float4*)(row + xbase + 4);

        // in-lane inclusive prefix of 8 elements
        float s0 = a.x;
        float s1 = s0 + a.y;
        float s2 = s1 + a.z;
        float s3 = s2 + a.w;
        float s4 = s3 + bb.x;
        float s5 = s4 + bb.y;
        float s6 = s5 + bb.z;
        float s7 = s6 + bb.w;

        // wave-inclusive scan of lane totals
        float incl = s7;
        #pragma unroll
        for (int off = 1; off < 64; off <<= 1) {
            float tt = __shfl_up(incl, off);
            if (lane >= off) incl += tt;
        }
        const float base = incl - s7;        // exclusive prefix
        s0 += base; s1 += base; s2 += base; s3 += base;
        s4 += base; s5 += base; s6 += base; s7 += base;
        // s_j = M[8*lane + j] inclusive row prefix

        const float total = __shfl(incl, 63);

        float hiv[8], lov[8];
        // hi taps: M[x+15]. x=8l+j: j=0 -> lane+1 elem7; j>=1 -> lane+2 elem j-1
        hiv[0] = __shfl_down(s7, 1);
        hiv[1] = __shfl_down(s0, 2);
        hiv[2] = __shfl_down(s1, 2);
        hiv[3] = __shfl_down(s2, 2);
        hiv[4] = __shfl_down(s3, 2);
        hiv[5] = __shfl_down(s4, 2);
        hiv[6] = __shfl_down(s5, 2);
        hiv[7] = __shfl_down(s6, 2);
        // lo taps: M[x-16] -> lane-2 elem j
        lov[0] = __shfl_up(s0, 2);
        lov[1] = __shfl_up(s1, 2);
        lov[2] = __shfl_up(s2, 2);
        lov[3] = __shfl_up(s3, 2);
        lov[4] = __shfl_up(s4, 2);
        lov[5] = __shfl_up(s5, 2);
        lov[6] = __shfl_up(s6, 2);
        lov[7] = __shfl_up(s7, 2);

        f16x8 hv;
        #pragma unroll
        for (int j = 0; j < 8; ++j) {
            const int x = xbase + j;
            const float mhi = (x + PP > WW - 1) ? total : hiv[j];
            const float mlo = (x - PP - 1 >= 0) ? lov[j] : 0.0f;
            hv[j] = (f16)(mhi - mlo);
        }
        *(f16x8*)&Hs[r][xbase] = hv;
    }
    __syncthreads();

    // ================= Phase 2: vertical running 31-sum + fused epilogue ===========
    // thread: 4 cols x 8 rows.  q = col group, g = row group.
    const int q  = t & 127;
    const int g  = t >> 7;               // 0..3
    const int c  = q * 4;
    const int r0 = g * 8;                // first output row (strip-relative)

    float4 B = make_float4(0.f, 0.f, 0.f, 0.f);
    #pragma unroll
    for (int j = 0; j < KK - 1; ++j) {   // H rows idx r0 .. r0+29
        const f16x4 h = *(const f16x4*)&Hs[r0 + j][c];
        B.x += (float)h[0]; B.y += (float)h[1]; B.z += (float)h[2]; B.w += (float)h[3];
    }

    float4 I4 = make_float4(0.f, 0.f, 0.f, 0.f);
    float4 U4 = make_float4(0.f, 0.f, 0.f, 0.f);
    const float inv2 = 1.0f / (float)(KK * KK);

    #pragma unroll
    for (int i = 0; i < 8; ++i) {
        const int y = y0 + r0 + i;
        const f16x4 he = *(const f16x4*)&Hs[r0 + i + (KK - 1)][c];
        const f16x4 hl = *(const f16x4*)&Hs[r0 + i][c];
        const float4 m4 = *(const float4*)(mb + (size_t)y * WW + c);   // L2-hot
        const float4 p4 = *(const float4*)(pb + (size_t)y * WW + c);

        B.x += (float)he[0]; B.y += (float)he[1]; B.z += (float)he[2]; B.w += (float)he[3];

        const float w0 = 1.0f + 5.0f * fabsf(B.x * inv2 - m4.x);
        const float w1 = 1.0f + 5.0f * fabsf(B.y * inv2 - m4.y);
        const float w2 = 1.0f + 5.0f * fabsf(B.z * inv2 - m4.z);
        const float w3 = 1.0f + 5.0f * fabsf(B.w * inv2 - m4.w);
        const float sg0 = 1.0f / (1.0f + __expf(-p4.x));
        const float sg1 = 1.0f / (1.0f + __expf(-p4.y));
        const float sg2 = 1.0f / (1.0f + __expf(-p4.z));
        const float sg3 = 1.0f / (1.0f + __expf(-p4.w));

        I4.x += sg0 * m4.x * w0;  U4.x += (sg0 + m4.x) * w0;
        I4.y += sg1 * m4.y * w1;  U4.y += (sg1 + m4.y) * w1;
        I4.z += sg2 * m4.z * w2;  U4.z += (sg2 + m4.z) * w2;
        I4.w += sg3 * m4.w * w3;  U4.w += (sg3 + m4.w) * w3;

        B.x -= (float)hl[0]; B.y -= (float)hl[1]; B.z -= (float)hl[2]; B.w -= (float)hl[3];
    }

    // ================= Block reduction -> per-block partials ======================
    float inter = I4.x + I4.y + I4.z + I4.w;
    float uni   = U4.x + U4.y + U4.z + U4.w;
    #pragma unroll
    for (int off = 32; off > 0; off >>= 1) {
        inter += __shfl_down(inter, off);
        uni   += __shfl_down(uni, off);
    }
    if (lane == 0) { red[wave] = inter; red[8 + wave] = uni; }
    __syncthreads();
    if (t == 0) {
        float ti = 0.f, tu = 0.f;
        #pragma unroll
        for (int w2 = 0; w2 < 8; ++w2) { ti += red[w2]; tu += red[8 + w2]; }
        const int bid = b * NSTRIP + strip;
        part[bid] = ti;
        part[NB * NSTRIP + bid] = tu;
    }
}

// ---------------- Final reduction ---------------
__global__ void dice_final_kernel(const float* __restrict__ part,
                                  float* __restrict__ out) {
    const int t = threadIdx.x;  // 64 threads, one per image
    float inter = 0.0f, uni = 0.0f;
    #pragma unroll
    for (int s = 0; s < NSTRIP; ++s) {
        inter += part[t * NSTRIP + s];
        uni   += part[NB * NSTRIP + t * NSTRIP + s];
    }
    float wd = 1.0f - (2.0f * inter + 0.5f) / (uni + 0.5f);
    #pragma unroll
    for (int off = 32; off > 0; off >>= 1) wd += __shfl_down(wd, off);
    if (t == 0) out[0] = wd * (1.0f / (float)NB);
}

extern "C" void kernel_launch(void* const* d_in, const int* in_sizes, int n_in,
                              void* d_out, int out_size, void* d_ws, size_t ws_size,
                              hipStream_t stream) {
    const float* pred = (const float*)d_in[0];
    const float* mask = (const float*)d_in[1];
    float* out  = (float*)d_out;
    float* part = (float*)d_ws;   // 2048 floats = 8 KB

    dim3 grid(NSTRIP, NB);        // 16 x 64 = 1024 blocks
    dice_fused_kernel<<<grid, 512, 0, stream>>>(pred, mask, part);
    dice_final_kernel<<<1, 64, 0, stream>>>(part, out);
}